// Round 8
// baseline (409.789 us; speedup 1.0000x reference)
//
#include <hip/hip_runtime.h>

// ModConv2D — StyleGAN2 modulated conv as implicit GEMM, f16 MFMA.
// B=16, H=W=64, CIN=COUT=256, 3x3 SAME, fp32 I/O.
//
// R8 = R7 + missing prologue barrier (s_style cross-wave race fix).
// Block = 128 M-positions x ALL 256 co (4 waves, wave tile 64x128).
//  - x window (4x66x32ci, modulated f16) staged once per ci-slice, dbuf.
//  - Wt relaid out as [c][t] contiguous 16 KB chunks; B staged to LDS with a
//    perfectly-coalesced 64 B/thread copy, double-buffered one tap ahead.
//  - ONE barrier per tap; 256 MFMAs/CU between barriers -> drains covered.
// Per-CU per-tap: MFMA 1242 cyc vs L2 ~585 + LDS ~670 -> MFMA-bound.

#define HH 64
#define WW 64
#define CI 256
#define CO 256
#define PITCH 36                     // ushorts: 32 data + 4 pad (72 B rows, <=2-way banks)
#define XCOLS 66
#define XSSZ (4 * XCOLS * PITCH)     // 9504 ushorts / buffer
#define BSSZ (256 * PITCH)           // 9216 ushorts / buffer

typedef float    f32x4 __attribute__((ext_vector_type(4)));
typedef _Float16 f16x8 __attribute__((ext_vector_type(8)));
typedef __fp16   fp16x2 __attribute__((ext_vector_type(2)));

__device__ __forceinline__ unsigned pk2(float a, float b) {
    fp16x2 h = __builtin_amdgcn_cvt_pkrtz(a, b);
    return __builtin_bit_cast(unsigned, h);
}

// ---- demod partial sums: scale2[b][co] += sum_ci (k*(s+1))^2, one tap/block ----
__global__ __launch_bounds__(256) void modscale_part(
    const float* __restrict__ kern,    // [9][CI][CO]
    const float* __restrict__ style,   // [B][CI]
    float* __restrict__ scale2)        // [B][CO], pre-zeroed
{
    const int b = blockIdx.x / 9;
    const int t = blockIdx.x - b * 9;
    const int tid = threadIdx.x;
    __shared__ float st[CI];
    st[tid] = style[b * CI + tid] + 1.0f;
    __syncthreads();
    float acc = 0.f;
    const float* kp = kern + (size_t)t * CI * CO + tid;
    #pragma unroll 8
    for (int ci = 0; ci < CI; ++ci) {
        float m = kp[ci * CO] * st[ci];
        acc += m * m;
    }
    atomicAdd(&scale2[b * CO + tid], acc);
}

// ---- weights -> f16, layout Wt2[cslice][tap][co][kk]: contiguous 16 KB chunks ----
__global__ __launch_bounds__(256) void prep_wt(const float* __restrict__ kern,
                                               ushort* __restrict__ Wt2) {
    __shared__ ushort tile[64][65];
    const int kt = blockIdx.x >> 2;        // 0..35 (64 k-values)
    const int ct = blockIdx.x & 3;         // 0..3  (64 co)
    const int k0 = kt * 64, c0 = ct * 64;
    const int tid = threadIdx.x;
    const int r = tid >> 2, q = tid & 3;

    const float* src = kern + (size_t)(k0 + r) * CO + c0 + q * 16;
    #pragma unroll
    for (int j = 0; j < 16; ++j) {
        _Float16 h = (_Float16)src[j];
        tile[q * 16 + j][r] = __builtin_bit_cast(unsigned short, h);  // [co_l][k_l]
    }
    __syncthreads();
    // thread (r=co_l, q): writes k = k0 + q*16 + j (contiguous 16-run)
    const int kbase = k0 + q * 16;
    const int t  = kbase >> 8;
    const int ci = kbase & 255;
    const int cs = ci >> 5;
    const int kk = ci & 31;
    ushort* dst = Wt2 + (((size_t)(cs * 9 + t) * 256 + c0 + r) * 32 + kk);
    #pragma unroll
    for (int j = 0; j < 16; ++j) dst[j] = tile[r][q * 16 + j];
}

// ---- implicit-GEMM conv: grid 512, block 256 (4 waves), tile 128M x 256N ----
__global__ __launch_bounds__(256, 2) void gemm_conv(
    const float* __restrict__ x,        // [B][H][W][CI] fp32
    const ushort* __restrict__ Wt2,     // [8][9][256][32] f16 chunks
    const float* __restrict__ style,    // [B][CI]
    const float* __restrict__ scale2,   // [B][CO] sum-of-squares
    float* __restrict__ y)              // [B][H][W][CO] fp32
{
    __shared__ __align__(16) ushort xs[2 * XSSZ];   // 38016 B
    __shared__ __align__(16) ushort bs[2 * BSSZ];   // 36864 B
    __shared__ float s_style[CI];

    const int tid  = threadIdx.x;
    const int lane = tid & 63;
    const int wave = tid >> 6;

    const int p0 = blockIdx.x * 128;     // 2 image rows of one sample
    const int b  = p0 >> 12;
    const int h0 = (p0 >> 6) & 63;

    s_style[tid] = style[b * CI + tid] + 1.0f;

    const int wm = (wave & 1) * 64;      // 0/64  (M)
    const int wn = (wave >> 1) * 128;    // 0/128 (N)
    const int fr = lane & 15;
    const int fq = lane >> 4;
    const int wrow  = wm >> 6;           // 0 or 1
    const int xlane = fq * 8;

    // stage 1/3 of the modulated x-window for slice c into buffer buf
    auto stage_xs_chunk = [&](int c, int buf, int chunk3) {
        ushort* dst = xs + buf * XSSZ;
        #pragma unroll
        for (int p = chunk3 * 3; p < chunk3 * 3 + 3; ++p) {
            const int task = p * 256 + tid;
            if (task < 2112) {
                const int rowcol = task >> 3;
                const int ch  = task & 7;
                const int row = rowcol / XCOLS;
                const int col = rowcol - row * XCOLS;
                const int rg = h0 - 1 + row;
                const int cg = col - 1;
                f32x4 v = {0.f, 0.f, 0.f, 0.f};
                if ((unsigned)rg < 64u && (unsigned)cg < 64u)
                    v = *(const f32x4*)(x + ((size_t)((b * HH + rg) * WW + cg)) * CI
                                          + c * 32 + ch * 4);
                const f32x4 st = *(const f32x4*)(s_style + c * 32 + ch * 4);
                const f32x4 m = v * st;
                uint2 u;
                u.x = pk2(m.x, m.y);
                u.y = pk2(m.z, m.w);
                *(uint2*)(dst + rowcol * PITCH + ch * 4) = u;
            }
        }
    };

    // stage 16 KB B chunk l: coalesced 64 B/thread
    auto stage_bs = [&](int l, int buf) {
        const ushort* src = Wt2 + (size_t)l * 8192 + tid * 32;
        uint4 v0 = *(const uint4*)(src);
        uint4 v1 = *(const uint4*)(src + 8);
        uint4 v2 = *(const uint4*)(src + 16);
        uint4 v3 = *(const uint4*)(src + 24);
        ushort* dst = bs + buf * BSSZ + tid * PITCH;
        *(uint4*)(dst)      = v0;
        *(uint4*)(dst + 8)  = v1;
        *(uint4*)(dst + 16) = v2;
        *(uint4*)(dst + 24) = v3;
    };

    f32x4 acc[4][8] = {};

    __syncthreads();   // s_style visible to ALL waves before staging reads it

    // prologue: full xs for c=0 + bs chunk 0
    stage_xs_chunk(0, 0, 0);
    stage_xs_chunk(0, 0, 1);
    stage_xs_chunk(0, 0, 2);
    stage_bs(0, 0);
    __syncthreads();

    for (int c = 0; c < 8; ++c) {
        const ushort* xb = xs + (c & 1) * XSSZ;
        #pragma unroll
        for (int t = 0; t < 9; ++t) {
            const int l = c * 9 + t;
            if (l < 71) stage_bs(l + 1, (l + 1) & 1);          // B prefetch, 1 tap ahead
            if (c < 7 && t < 3) stage_xs_chunk(c + 1, (c + 1) & 1, t);  // x prefetch

            const ushort* bsb = bs + (l & 1) * BSSZ;
            const int dh = t / 3;
            const int dw = t - dh * 3;

            f16x8 af[4], bf[8];
            const ushort* ab = xb + ((wrow + dh) * XCOLS + fr + dw) * PITCH + xlane;
            #pragma unroll
            for (int i = 0; i < 4; ++i)
                af[i] = *(const f16x8*)(ab + i * 16 * PITCH);
            #pragma unroll
            for (int j = 0; j < 8; ++j)
                bf[j] = *(const f16x8*)(bsb + (wn + j * 16 + fr) * PITCH + fq * 8);
            #pragma unroll
            for (int i = 0; i < 4; ++i)
                #pragma unroll
                for (int j = 0; j < 8; ++j)
                    acc[i][j] = __builtin_amdgcn_mfma_f32_16x16x32_f16(
                        af[i], bf[j], acc[i][j], 0, 0, 0);
            __syncthreads();
        }
    }

    // ---- epilogue: demod + store. D: col=lane&15, row=(lane>>4)*4+reg ----
    float sc[8];
    #pragma unroll
    for (int j = 0; j < 8; ++j)
        sc[j] = __frsqrt_rn(scale2[b * CO + wn + j * 16 + fr] + 1e-8f);
    #pragma unroll
    for (int i = 0; i < 4; ++i) {
        const int m_base = p0 + wm + i * 16 + fq * 4;
        #pragma unroll
        for (int j = 0; j < 8; ++j) {
            float* yp = y + (size_t)m_base * CO + wn + j * 16 + fr;
            #pragma unroll
            for (int r = 0; r < 4; ++r)
                yp[(size_t)r * CO] = acc[i][j][r] * sc[j];
        }
    }
}

extern "C" void kernel_launch(void* const* d_in, const int* in_sizes, int n_in,
                              void* d_out, int out_size, void* d_ws, size_t ws_size,
                              hipStream_t stream) {
    const float* x     = (const float*)d_in[0];  // [16,64,64,256]
    const float* style = (const float*)d_in[1];  // [16,256]
    const float* kern  = (const float*)d_in[2];  // [3,3,256,256]
    float* out = (float*)d_out;                  // [16,64,64,256]

    float*  scale2 = (float*)d_ws;                       // 16*256 fp32
    ushort* Wt2    = (ushort*)((char*)d_ws + 16384);     // 72 chunks x 16 KB

    hipMemsetAsync(scale2, 0, 16 * CO * sizeof(float), stream);
    modscale_part<<<16 * 9, 256, 0, stream>>>(kern, style, scale2);
    prep_wt<<<144, 256, 0, stream>>>(kern, Wt2);
    gemm_conv<<<512, 256, 0, stream>>>(x, Wt2, style, scale2, out);
}

// Round 9
// 288.026 us; speedup vs baseline: 1.4228x; 1.4228x over previous
//
#include <hip/hip_runtime.h>

// ModConv2D — StyleGAN2 modulated conv as implicit GEMM, f16 MFMA.
// B=16, H=W=64, CIN=COUT=256, 3x3 SAME, fp32 I/O.
//
// R9: software-pipelined taps. Per tap: issue global loads (B chunk + 1/5 of
// next x-window) FIRST, run 16 MFMAs, THEN ds_write the staged data, barrier.
// The vmcnt wait sits behind the MFMA burst instead of in front of it (R8 bug).
// 1024 blocks (128M x 128N), 4 waves of 64x64, unpadded 64-B LDS cells
// (contiguous-1KB b128 patterns = conflict-free), 50 KB LDS -> 3 blocks/CU.

#define HH 64
#define WW 64
#define CI 256
#define CO 256
#define XSW 8448      // ushorts per xs buffer: 264 cells * 32
#define BSW 4096      // ushorts per bs buffer: 128 co * 32

typedef float    f32x4 __attribute__((ext_vector_type(4)));
typedef _Float16 f16x8 __attribute__((ext_vector_type(8)));
typedef __fp16   fp16x2 __attribute__((ext_vector_type(2)));

__device__ __forceinline__ unsigned pk2(float a, float b) {
    fp16x2 h = __builtin_amdgcn_cvt_pkrtz(a, b);
    return __builtin_bit_cast(unsigned, h);
}

// ---- fused prep: blk 0..143 = Wt2 transpose+f16; blk 144..159 = demod scale ----
__global__ __launch_bounds__(256) void prep_kernel(
    const float* __restrict__ kern,    // [9][CI][CO] = [2304][256]
    const float* __restrict__ style,   // [B][CI]
    ushort* __restrict__ Wt2,          // [8][9][256 co][32 kk] f16
    float* __restrict__ scale)         // [B][CO] final rsqrt factor
{
    const int blk = blockIdx.x;
    const int tid = threadIdx.x;
    if (blk < 144) {
        __shared__ ushort tile[64][65];
        const int kt = blk >> 2, ct = blk & 3;
        const int k0 = kt * 64, c0 = ct * 64;
        const int r = tid >> 2, q = tid & 3;
        const float* src = kern + (size_t)(k0 + r) * CO + c0 + q * 16;
        #pragma unroll
        for (int j = 0; j < 16; ++j) {
            _Float16 h = (_Float16)src[j];
            tile[q * 16 + j][r] = __builtin_bit_cast(unsigned short, h);
        }
        __syncthreads();
        const int kbase = k0 + q * 16;          // k = t*256 + ci, 16-contiguous
        const int t  = kbase >> 8;
        const int ci = kbase & 255;
        const int cs = ci >> 5, kk = ci & 31;
        ushort* dst = Wt2 + (((size_t)(cs * 9 + t) * 256 + c0 + r) * 32 + kk);
        #pragma unroll
        for (int j = 0; j < 16; ++j) dst[j] = tile[r][q * 16 + j];
    } else {
        const int b = blk - 144;
        __shared__ float st[CI];
        st[tid] = style[b * CI + tid] + 1.0f;
        __syncthreads();
        float acc = 0.f;
        const float* kp = kern + tid;           // column co=tid
        #pragma unroll 8
        for (int k = 0; k < 2304; ++k) {
            float m = kp[(size_t)k * CO] * st[k & 255];
            acc += m * m;
        }
        scale[b * CO + tid] = 1.0f / sqrtf(acc + 1e-8f);
    }
}

// ---- implicit-GEMM conv: 1024 blocks, 256 thr, tile 128M x 128N ----
__global__ __launch_bounds__(256, 3) void gemm_conv(
    const float* __restrict__ x,        // [B][H][W][CI] fp32
    const ushort* __restrict__ Wt2,     // [8][9][256][32] f16
    const float* __restrict__ style,    // [B][CI]
    const float* __restrict__ scale,    // [B][CO]
    float* __restrict__ y)              // [B][H][W][CO] fp32
{
    __shared__ __align__(16) ushort xs[2 * XSW];   // 33792 B
    __shared__ __align__(16) ushort bs[2 * BSW];   // 16384 B
    __shared__ float s_style[CI];                  // 1024 B

    const int tid  = threadIdx.x;
    const int lane = tid & 63;
    const int wave = tid >> 6;

    const int mtile = blockIdx.x >> 1;
    const int n0    = (blockIdx.x & 1) * 128;
    const int p0    = mtile * 128;
    const int b     = p0 >> 12;
    const int h0    = (p0 >> 6) & 63;

    s_style[tid] = style[b * CI + tid] + 1.0f;

    const int wm = (wave & 1) * 64, wn = (wave >> 1) * 64;
    const int fr = lane & 15, fq = lane >> 4;
    const int wrow = wm >> 6;

    // x-window staging units: u = g*256+tid, g<4 always, g==4 only tid<32.
    // unit u -> cell u>>2 (row=cell/66,col=cell%66), quarter q=u&3 (8 ci).
    int  ubase[5], uq[5];
    bool uval[5];
    #pragma unroll
    for (int g = 0; g < 5; ++g) {
        const int u = g * 256 + tid;
        const int cell = u >> 2, q = u & 3;
        const int row = cell / 66;
        const int col = cell - 66 * row;
        const int rg = h0 - 1 + row, cg = col - 1;
        const bool act = (g < 4) || (tid < 32);
        uval[g]  = act && ((unsigned)rg < 64u) && ((unsigned)cg < 64u);
        ubase[g] = ((b * 4096 + rg * 64 + cg) << 8) + q * 8;   // f32 index sans c*32
        uq[g]    = q * 8;
    }

    f32x4 acc[4][4] = {};
    f32x4 rr0, rr1;        // in-flight x regs (one group live at a time)
    uint4 rb0, rb1;        // in-flight B regs

    auto xs_load = [&](int c, int g) {
        if (uval[g]) {
            const float* p = x + ubase[g] + c * 32;
            rr0 = *(const f32x4*)(p);
            rr1 = *(const f32x4*)(p + 4);
        } else {
            rr0 = (f32x4){0.f, 0.f, 0.f, 0.f};
            rr1 = rr0;
        }
    };
    auto xs_write = [&](int c, int g, int buf) {
        const bool act = (g < 4) || (tid < 32);
        if (act) {
            const f32x4 s0 = *(const f32x4*)(s_style + c * 32 + uq[g]);
            const f32x4 s1 = *(const f32x4*)(s_style + c * 32 + uq[g] + 4);
            const f32x4 m0 = rr0 * s0, m1 = rr1 * s1;
            uint4 u;
            u.x = pk2(m0.x, m0.y); u.y = pk2(m0.z, m0.w);
            u.z = pk2(m1.x, m1.y); u.w = pk2(m1.z, m1.w);
            *(uint4*)(xs + buf * XSW + (g * 256 + tid) * 8) = u;
        }
    };
    auto bs_load = [&](int l) {
        const ushort* src = Wt2 + (size_t)l * 8192 + n0 * 32 + tid * 16;
        rb0 = *(const uint4*)(src);
        rb1 = *(const uint4*)(src + 8);
    };
    auto bs_write = [&](int l) {
        ushort* d = bs + (l & 1) * BSW + tid * 16;
        *(uint4*)(d)     = rb0;
        *(uint4*)(d + 8) = rb1;
    };

    __syncthreads();   // s_style visible before any staging reads it

    // prologue: slice 0 x-window + B chunk 0
    #pragma unroll
    for (int g = 0; g < 5; ++g) { xs_load(0, g); xs_write(0, g, 0); }
    bs_load(0); bs_write(0);
    __syncthreads();

    for (int c = 0; c < 8; ++c) {
        const ushort* xb = xs + (c & 1) * XSW;
        #pragma unroll
        for (int t = 0; t < 9; ++t) {
            const int l = c * 9 + t;
            // issue next-stage global loads FIRST (fly during MFMAs)
            if (l < 71) bs_load(l + 1);
            const bool do_xs = (c < 7) && (t < 5);
            if (do_xs) xs_load(c + 1, t);

            const int dh = t / 3, dw = t - 3 * (t / 3);
            f16x8 af[4], bf[4];
            const int arow = (wrow + dh) * 66;
            #pragma unroll
            for (int i = 0; i < 4; ++i)
                af[i] = *(const f16x8*)(xb + (arow + i * 16 + fr + dw) * 32 + fq * 8);
            const ushort* bsb = bs + (l & 1) * BSW;
            #pragma unroll
            for (int j = 0; j < 4; ++j)
                bf[j] = *(const f16x8*)(bsb + (wn + j * 16 + fr) * 32 + fq * 8);
            #pragma unroll
            for (int i = 0; i < 4; ++i)
                #pragma unroll
                for (int j = 0; j < 4; ++j)
                    acc[i][j] = __builtin_amdgcn_mfma_f32_16x16x32_f16(
                        af[i], bf[j], acc[i][j], 0, 0, 0);

            // drain staged data into LDS AFTER the burst, then barrier
            if (l < 71) bs_write(l + 1);
            if (do_xs) xs_write(c + 1, t, (c + 1) & 1);
            __syncthreads();
        }
    }

    // ---- epilogue: D col=lane&15, row=(lane>>4)*4+reg ----
    float sc[4];
    #pragma unroll
    for (int j = 0; j < 4; ++j)
        sc[j] = scale[b * CO + n0 + wn + j * 16 + fr];
    #pragma unroll
    for (int i = 0; i < 4; ++i) {
        const int m_base = p0 + wm + i * 16 + fq * 4;
        #pragma unroll
        for (int j = 0; j < 4; ++j) {
            float* yp = y + (size_t)m_base * CO + n0 + wn + j * 16 + fr;
            #pragma unroll
            for (int r = 0; r < 4; ++r)
                yp[(size_t)r * CO] = acc[i][j][r] * sc[j];
        }
    }
}

extern "C" void kernel_launch(void* const* d_in, const int* in_sizes, int n_in,
                              void* d_out, int out_size, void* d_ws, size_t ws_size,
                              hipStream_t stream) {
    const float* x     = (const float*)d_in[0];  // [16,64,64,256]
    const float* style = (const float*)d_in[1];  // [16,256]
    const float* kern  = (const float*)d_in[2];  // [3,3,256,256]
    float* out = (float*)d_out;                  // [16,64,64,256]

    float*  scale = (float*)d_ws;                        // 16*256 fp32 = 16 KB
    ushort* Wt2   = (ushort*)((char*)d_ws + 16384);      // 72 x 16 KB f16 chunks

    prep_kernel<<<160, 256, 0, stream>>>(kern, style, Wt2, scale);
    gemm_conv<<<1024, 256, 0, stream>>>(x, Wt2, style, scale, out);
}